// Round 14
// baseline (1104.163 us; speedup 1.0000x reference)
//
#include <hip/hip_runtime.h>
#include <hip/hip_bf16.h>

#define NMESH 50000
#define GRIDN 32768
#define NEDGE 131072
#define HID 384

using f32x4 = __attribute__((ext_vector_type(4))) float;
using bfrag = __attribute__((ext_vector_type(8))) short;

__device__ __forceinline__ float gelu_f(float v) {
    return 0.5f * v * (1.0f + erff(v * 0.70710678118654752f));
}

__device__ __forceinline__ void load_lds16(const void* g, void* l) {
    __builtin_amdgcn_global_load_lds(
        (const __attribute__((address_space(1))) void*)g,
        (__attribute__((address_space(3))) void*)l,
        16, 0, 0);
}

// bijective XCD-chunking swizzle (m204)
__device__ __forceinline__ void xcd_swizzle(int& bx, int& by) {
    int gx = gridDim.x;
    int nwg = gx * gridDim.y;
    int l = blockIdx.y * gx + blockIdx.x;
    int q = nwg >> 3, r = nwg & 7;
    int xcd = l & 7, pos = l >> 3;
    int nl = (xcd < r ? xcd * (q + 1) : r * (q + 1) + (xcd - r) * q) + pos;
    by = nl / gx;
    bx = nl - by * gx;
}

// ---------------- weight transpose + bf16 cast: wt[n*K+k] = w[(k0+k)*N+n] ----------------
__global__ void transpose_to_bf16(const float* __restrict__ w, __hip_bfloat16* __restrict__ wt,
                                  int K, int N, int k0) {
    int idx = blockIdx.x * blockDim.x + threadIdx.x;
    if (idx >= K * N) return;
    int n = idx / K;
    int k = idx - n * K;
    wt[idx] = __float2bfloat16(w[(size_t)(k0 + k) * N + n]);
}

// ---------------- fold w3 into wm1: wtf[n*576+k] = (w3@wm1[:384])[k,n] (k<384) | wm1[k,n] ----------------
__global__ void fold_w3_wm1(const float* __restrict__ w3, const float* __restrict__ wm1,
                            __hip_bfloat16* __restrict__ wtf) {
    int idx = blockIdx.x * blockDim.x + threadIdx.x;   // idx = k*768 + n (wm1 reads coalesced over n)
    if (idx >= 576 * 768) return;
    int k = idx / 768;
    int n = idx - k * 768;
    float acc;
    if (k < 384) {
        acc = 0.f;
        for (int j = 0; j < 384; j++)
            acc = fmaf(w3[k * 384 + j], wm1[j * 768 + n], acc);
    } else {
        acc = wm1[(size_t)k * 768 + n];
    }
    wtf[(size_t)n * 576 + k] = __float2bfloat16(acc);
}

// ---------------- folded bias: bf[n] = bm1[n] + sum_k b3[k]*wm1[k,n] ----------------
__global__ void fold_bias(const float* __restrict__ b3, const float* __restrict__ wm1,
                          const float* __restrict__ bm1, float* __restrict__ bf) {
    int n = blockIdx.x * blockDim.x + threadIdx.x;
    if (n >= 768) return;
    float acc = bm1[n];
    for (int k = 0; k < 384; k++) acc = fmaf(b3[k], wm1[(size_t)k * 768 + n], acc);
    bf[n] = acc;
}

// ---------------- rowstart[g] = lower_bound(edges[:,0], g), g in [0, GRIDN] ----------------
__global__ void calc_rowstart(const int* __restrict__ edges, int* __restrict__ rs) {
    int g = blockIdx.x * blockDim.x + threadIdx.x;
    if (g > GRIDN) return;
    int l = 0, r = NEDGE;
    while (l < r) { int m = (l + r) >> 1; if (edges[2 * m] < g) l = m + 1; else r = m; }
    rs[g] = l;
}

// ---------------- sincos positional embedding ----------------
__global__ void embed_kernel(const float* __restrict__ pos, __hip_bfloat16* __restrict__ outp,
                             int n, int stride, int coloff) {
    int idx = blockIdx.x * blockDim.x + threadIdx.x;
    if (idx >= n * 96) return;
    int nn = idx / 96;
    int rr = idx - nn * 96;
    int d = rr >> 5;
    int k = rr & 31;
    float v = pos[nn * 3 + d];
    float omega = expf(-0.28782313662425575f * (float)k);  // ln(10000)/32
    float a = v * omega;
    __hip_bfloat16* o = outp + (size_t)nn * stride + coloff + d * 64 + k;
    o[0]  = __float2bfloat16(sinf(a));
    o[32] = __float2bfloat16(cosf(a));
}

// ---------------- layer 1: h1 = gelu(x @ w1 + b1), K=16 ----------------
__global__ void lin1_kernel(const float* __restrict__ x, const float* __restrict__ w,
                            const float* __restrict__ b, __hip_bfloat16* __restrict__ h1) {
    int idx = blockIdx.x * blockDim.x + threadIdx.x;
    if (idx >= NMESH * HID) return;
    int m = idx / HID;
    int n = idx - m * HID;
    float acc = b[n];
    const float* xr = x + m * 16;
    #pragma unroll
    for (int k = 0; k < 16; k++) acc = fmaf(xr[k], w[k * HID + n], acc);
    h1[idx] = __float2bfloat16(gelu_f(acc));
}

// ======================================================================
// 128x128-tile bf16 MFMA GEMM (round-11/12/13 proven body, unchanged).
// 3-buffer counted-vmcnt pipeline, pre-swizzled global_load_lds
// (measured: 0 bank conflicts, no spill). C = act(A @ Wt^T + bias).
// ======================================================================
template<bool GELU, bool F32OUT>
__launch_bounds__(256, 3)
__global__ void mfma_gemm(const __hip_bfloat16* __restrict__ A,
                          const __hip_bfloat16* __restrict__ Wt,
                          const float* __restrict__ bias,
                          void* __restrict__ Cv,
                          int M, int N, int K, int ldc) {
    __shared__ __align__(16) __hip_bfloat16 As[3][4096];
    __shared__ __align__(16) __hip_bfloat16 Bs[3][4096];

    const int t = threadIdx.x;
    const int lane = t & 63;
    const int wave = t >> 6;
    const int wm0 = (wave >> 1) * 64;
    const int wn0 = (wave & 1) * 64;

    int bx, by;
    xcd_swizzle(bx, by);
    const int row0 = by * 128;
    const int col0 = bx * 128;

    const int rS0 = t >> 2;
    const int rS1 = rS0 + 64;
    const int kcS = (t & 3) ^ ((t >> 3) & 3);

    const __hip_bfloat16* aP0 = A + (size_t)min(row0 + rS0, M - 1) * K;
    const __hip_bfloat16* aP1 = A + (size_t)min(row0 + rS1, M - 1) * K;
    const __hip_bfloat16* bP0 = Wt + (size_t)(col0 + rS0) * K;
    const __hip_bfloat16* bP1 = Wt + (size_t)(col0 + rS1) * K;

    const int off0 = (wave * 64) * 16;
    const int off1 = (256 + wave * 64) * 16;

    f32x4 acc[4][4] = {};

    const int kq = lane >> 4;
    const int lr = lane & 15;
    const int kqx = kq ^ ((lr >> 1) & 3);
    const int rdA = (wm0 + lr) * 32 + kqx * 8;
    const int rdB = (wn0 + lr) * 32 + kqx * 8;

    const int nsteps = K >> 5;

    auto stage = [&](int ks, int buf) {
        int k = ks * 32 + kcS * 8;
        load_lds16(aP0 + k, (char*)As[buf] + off0);
        load_lds16(aP1 + k, (char*)As[buf] + off1);
        load_lds16(bP0 + k, (char*)Bs[buf] + off0);
        load_lds16(bP1 + k, (char*)Bs[buf] + off1);
    };

    stage(0, 0);
    stage(1, 1);

    int cur = 0;
    int stg = 2;
    for (int ks = 0; ks < nsteps; ks++) {
        if (ks + 1 < nsteps) {
            asm volatile("s_waitcnt vmcnt(4)" ::: "memory");
        } else {
            asm volatile("s_waitcnt vmcnt(0)" ::: "memory");
        }
        __builtin_amdgcn_s_barrier();
        if (ks + 2 < nsteps) stage(ks + 2, stg);

        bfrag aF[4], bF[4];
        #pragma unroll
        for (int i = 0; i < 4; i++) {
            aF[i] = *reinterpret_cast<const bfrag*>(&As[cur][rdA + i * 512]);
            bF[i] = *reinterpret_cast<const bfrag*>(&Bs[cur][rdB + i * 512]);
        }
        asm volatile("s_waitcnt lgkmcnt(0)" ::: "memory");
        __builtin_amdgcn_sched_barrier(0);
        __builtin_amdgcn_s_setprio(1);
        #pragma unroll
        for (int i = 0; i < 4; i++) {
            #pragma unroll
            for (int j = 0; j < 4; j++) {
                acc[i][j] = __builtin_amdgcn_mfma_f32_16x16x32_bf16(aF[i], bF[j], acc[i][j], 0, 0, 0);
            }
        }
        __builtin_amdgcn_s_setprio(0);

        cur = (cur == 2) ? 0 : cur + 1;
        stg = (stg == 2) ? 0 : stg + 1;
    }

    #pragma unroll
    for (int i = 0; i < 4; i++) {
        #pragma unroll
        for (int j = 0; j < 4; j++) {
            #pragma unroll
            for (int r = 0; r < 4; r++) {
                int row = row0 + wm0 + i * 16 + kq * 4 + r;
                int col = col0 + wn0 + j * 16 + lr;
                if (row < M) {
                    float v = acc[i][j][r] + bias[col];
                    if constexpr (GELU) v = gelu_f(v);
                    if constexpr (F32OUT)
                        ((float*)Cv)[(size_t)row * ldc + col] = v;
                    else
                        ((__hip_bfloat16*)Cv)[(size_t)row * ldc + col] = __float2bfloat16(v);
                }
            }
        }
    }
}

// ---------------- m1 fuse: m1c[e] = gelu(U[mesh_idx[e]] + V[grid_idx[e]]) ----------------
__global__ void fuse_m1(const __hip_bfloat16* __restrict__ U, const __hip_bfloat16* __restrict__ V,
                        const int* __restrict__ edges, int e0, int ne,
                        __hip_bfloat16* __restrict__ m1c) {
    int idx = blockIdx.x * blockDim.x + threadIdx.x;
    if (idx >= ne * 96) return;
    int e = idx / 96;
    int c8 = (idx - e * 96) * 8;
    int ge = e0 + e;
    int mi = edges[2 * ge + 1];
    int gi = edges[2 * ge + 0];
    bfrag u = *reinterpret_cast<const bfrag*>(U + (size_t)mi * 768 + c8);
    bfrag v = *reinterpret_cast<const bfrag*>(V + (size_t)gi * 768 + c8);
    bfrag o;
    #pragma unroll
    for (int i = 0; i < 8; i++) {
        unsigned short ub = (unsigned short)u[i], vb = (unsigned short)v[i];
        float a = __bfloat162float(*(__hip_bfloat16*)&ub) + __bfloat162float(*(__hip_bfloat16*)&vb);
        a = gelu_f(a);
        __hip_bfloat16 hb = __float2bfloat16(a);
        o[i] = *(short*)&hb;
    }
    *reinterpret_cast<bfrag*>(m1c + (size_t)e * 768 + c8) = o;
}

// ---------------- per-chunk 768-wide f32 segment partial sums (rowstart-based, 8 cells/block) ----------------
__global__ void seg768(const int* __restrict__ rs, int e0, int e1,
                       const __hip_bfloat16* __restrict__ m2c, float* __restrict__ sums) {
    int gbase = blockIdx.x * 8;
    int c = threadIdx.x;   // 256 threads, 3 cols each
    #pragma unroll 1
    for (int gg = 0; gg < 8; gg++) {
        int g = gbase + gg;
        int lo = max(rs[g], e0);
        int hi = min(rs[g + 1], e1);
        if (lo >= hi) continue;
        float s0 = 0.f, s1 = 0.f, s2 = 0.f;
        for (int e = lo; e < hi; e++) {
            const __hip_bfloat16* rp = m2c + (size_t)(e - e0) * 768;
            s0 += __bfloat162float(rp[c]);
            s1 += __bfloat162float(rp[c + 256]);
            s2 += __bfloat162float(rp[c + 512]);
        }
        float* srow = sums + (size_t)g * 768;
        srow[c] += s0;
        srow[c + 256] += s1;
        srow[c + 512] += s2;
    }
}

// ---------------- meanM2 = bf16(sums / max(cnt,1)) ----------------
__global__ void mean_bf16(const float* __restrict__ sums, const int* __restrict__ rs,
                          __hip_bfloat16* __restrict__ mm) {
    int idx = blockIdx.x * blockDim.x + threadIdx.x;
    int base = idx * 4;
    if (base >= GRIDN * 768) return;
    int g = base / 768;
    int cnt = rs[g + 1] - rs[g];
    float inv = 1.0f / (float)max(cnt, 1);
    float4 v = *reinterpret_cast<const float4*>(sums + base);
    __hip_bfloat16 o[4] = {__float2bfloat16(v.x * inv), __float2bfloat16(v.y * inv),
                           __float2bfloat16(v.z * inv), __float2bfloat16(v.w * inv)};
    *reinterpret_cast<uint2*>(mm + base) = *reinterpret_cast<const uint2*>(o);
}

// ---------------- zero output rows of empty segments (bias added unconditionally) ----------------
__global__ void fix_empty(const int* __restrict__ rs, float* __restrict__ out) {
    int g = blockIdx.x * blockDim.x + threadIdx.x;
    if (g >= GRIDN || (rs[g + 1] - rs[g]) != 0) return;
    float* row = out + (size_t)g * HID;
    for (int c = 0; c < HID; c++) row[c] = 0.f;
}

// ---------------- fallback: 384-wide seg machinery (proven) ----------------
__global__ void seg_partial(const int* __restrict__ edges, int e0, int e1,
                            const __hip_bfloat16* __restrict__ m3c, float* __restrict__ out) {
    int g = blockIdx.x;
    int l = e0, r = e1;
    while (l < r) { int mid = (l + r) >> 1; if (edges[2 * mid] < g) l = mid + 1; else r = mid; }
    int lo = l;
    r = e1;
    while (l < r) { int mid = (l + r) >> 1; if (edges[2 * mid] <= g) l = mid + 1; else r = mid; }
    int hi = l;
    if (lo >= hi) return;
    int c = threadIdx.x;
    float s0 = 0.f, s1 = 0.f, s2 = 0.f;
    for (int e = lo; e < hi; e++) {
        const __hip_bfloat16* rp = m3c + (size_t)(e - e0) * HID;
        s0 += __bfloat162float(rp[c]);
        s1 += __bfloat162float(rp[c + 128]);
        s2 += __bfloat162float(rp[c + 256]);
    }
    float* orow = out + (size_t)g * HID;
    orow[c] += s0;
    orow[c + 128] += s1;
    orow[c + 256] += s2;
}

__global__ void seg_div(const int* __restrict__ edges, float* __restrict__ out) {
    int g = blockIdx.x;
    int l = 0, r = NEDGE;
    while (l < r) { int mid = (l + r) >> 1; if (edges[2 * mid] < g) l = mid + 1; else r = mid; }
    int lo = l;
    r = NEDGE;
    while (l < r) { int mid = (l + r) >> 1; if (edges[2 * mid] <= g) l = mid + 1; else r = mid; }
    int cnt = l - lo;
    float inv = 1.0f / (float)max(cnt, 1);
    int c = threadIdx.x;
    float* orow = out + (size_t)g * HID;
    orow[c] *= inv;
    orow[c + 128] *= inv;
    orow[c + 256] *= inv;
}

extern "C" void kernel_launch(void* const* d_in, const int* in_sizes, int n_in,
                              void* d_out, int out_size, void* d_ws, size_t ws_size,
                              hipStream_t stream) {
    const float* x        = (const float*)d_in[0];
    const float* mesh_pos = (const float*)d_in[1];
    const float* grid_pos = (const float*)d_in[2];
    const int*   edges    = (const int*)d_in[3];
    const float* w1  = (const float*)d_in[4];
    const float* b1  = (const float*)d_in[5];
    const float* w2  = (const float*)d_in[6];
    const float* b2  = (const float*)d_in[7];
    const float* w3  = (const float*)d_in[8];
    const float* b3  = (const float*)d_in[9];
    const float* wm1 = (const float*)d_in[10];
    const float* bm1 = (const float*)d_in[11];
    const float* wm2 = (const float*)d_in[12];
    const float* bm2 = (const float*)d_in[13];
    const float* wm3 = (const float*)d_in[14];
    const float* bm3 = (const float*)d_in[15];
    float* out = (float*)d_out;

    auto rnd = [](size_t b) { return (b + 255) & ~(size_t)255; };
    const size_t wbytes = rnd((size_t)384 * 384 * 2) + rnd((size_t)768 * 576 * 2) +
                          rnd((size_t)768 * 192 * 2) + rnd((size_t)768 * 768 * 2) +
                          rnd((size_t)384 * 768 * 2) + rnd(768 * 4) * 2 +
                          rnd((size_t)(GRIDN + 1) * 4);
    const size_t szU    = rnd((size_t)NMESH * 768 * 2);     // 76.8 MB
    const size_t szV    = rnd((size_t)GRIDN * 768 * 2);     // 50.33 MB
    const size_t szMesh = rnd((size_t)NMESH * 576 * 2);     // 57.6 MB
    const size_t szSums = rnd((size_t)GRIDN * 768 * 4);     // 100.66 MB

    const size_t NEED_FOLD = wbytes + szU + szV + szSums + 2 * rnd((size_t)16384 * 768 * 2);

    char* p = (char*)d_ws;
    auto alloc = [&](size_t b) { char* r = p; p += (b + 255) & ~(size_t)255; return r; };

    // common prep allocations
    __hip_bfloat16* wt2   = (__hip_bfloat16*)alloc((size_t)384 * 384 * 2);
    __hip_bfloat16* wtm1f = (__hip_bfloat16*)alloc((size_t)768 * 576 * 2);  // folded [n=768][k=576]
    __hip_bfloat16* wtm1v = (__hip_bfloat16*)alloc((size_t)768 * 192 * 2);
    __hip_bfloat16* wtm2  = (__hip_bfloat16*)alloc((size_t)768 * 768 * 2);
    __hip_bfloat16* wtm3  = (__hip_bfloat16*)alloc((size_t)384 * 768 * 2);
    float* zeros          = (float*)alloc(768 * 4);
    float* bf             = (float*)alloc(768 * 4);
    int* rs               = (int*)alloc((size_t)(GRIDN + 1) * 4);
    char* Ur              = alloc(szU);
    char* Vr              = alloc(szV);

    __hip_bfloat16* U  = (__hip_bfloat16*)Ur;
    __hip_bfloat16* V  = (__hip_bfloat16*)Vr;
    __hip_bfloat16* h1 = (__hip_bfloat16*)Ur;                 // [0, 38.4 MB), dead before U

    hipMemsetAsync(zeros, 0, 768 * 4, stream);

    transpose_to_bf16<<<(384 * 384 + 255) / 256, 256, 0, stream>>>(w2, wt2, 384, 384, 0);
    transpose_to_bf16<<<(768 * 192 + 255) / 256, 256, 0, stream>>>(wm1, wtm1v, 192, 768, 576);
    transpose_to_bf16<<<(768 * 768 + 255) / 256, 256, 0, stream>>>(wm2, wtm2, 768, 768, 0);
    transpose_to_bf16<<<(768 * 384 + 255) / 256, 256, 0, stream>>>(wm3, wtm3, 768, 384, 0);
    fold_w3_wm1<<<(576 * 768 + 255) / 256, 256, 0, stream>>>(w3, wm1, wtm1f);
    fold_bias<<<3, 256, 0, stream>>>(b3, wm1, bm1, bf);
    calc_rowstart<<<(GRIDN + 1 + 255) / 256, 256, 0, stream>>>(edges, rs);

    if (ws_size >= NEED_FOLD) {
        // ================= FOLD PATH: w3-folded U/V + linear-m3 folding, CH=16384 =================
        const int CH = 16384;
        const int NCH = NEDGE / CH;
        char* SR = alloc(szSums);                       // sums region (embeds overlay here)
        char* CA = alloc(2 * rnd((size_t)CH * 768 * 2));

        float* sums            = (float*)SR;
        __hip_bfloat16* meshf2 = (__hip_bfloat16*)SR;            // [h2 | pe], dead after U-GEMM
        __hip_bfloat16* gridf  = (__hip_bfloat16*)(SR + szMesh); // dead after V-GEMM
        __hip_bfloat16* m1c    = (__hip_bfloat16*)CA;
        __hip_bfloat16* m2c    = (__hip_bfloat16*)(CA + rnd((size_t)CH * 768 * 2));
        __hip_bfloat16* meanM2 = (__hip_bfloat16*)CA;            // spans m1c+m2c (both dead)

        embed_kernel<<<(NMESH * 96 + 255) / 256, 256, 0, stream>>>(mesh_pos, meshf2, NMESH, 576, 384);
        embed_kernel<<<(GRIDN * 96 + 255) / 256, 256, 0, stream>>>(grid_pos, gridf, GRIDN, 192, 0);

        lin1_kernel<<<(NMESH * HID + 255) / 256, 256, 0, stream>>>(x, w1, b1, h1);

        // meshf2[:, :384] = h2 = gelu(h1 @ w2 + b2)   (ldc=576)
        mfma_gemm<true, false><<<dim3(3, 391), 256, 0, stream>>>(
            h1, wt2, b2, meshf2, NMESH, 384, 384, 576);
        // U = meshf2 @ Wfold + bf   (w3 folded in; overwrites h1 -- dead)
        mfma_gemm<false, false><<<dim3(6, 391), 256, 0, stream>>>(
            meshf2, wtm1f, bf, U, NMESH, 768, 576, 768);
        // V = gridf @ wm1[576:]
        mfma_gemm<false, false><<<dim3(6, 256), 256, 0, stream>>>(
            gridf, wtm1v, zeros, V, GRIDN, 768, 192, 768);

        hipMemsetAsync(sums, 0, (size_t)GRIDN * 768 * 4, stream);  // embeds now dead

        for (int c = 0; c < NCH; c++) {
            int e0 = c * CH;
            fuse_m1<<<(CH * 96 + 255) / 256, 256, 0, stream>>>(U, V, edges, e0, CH, m1c);
            mfma_gemm<true, false><<<dim3(6, CH / 128), 256, 0, stream>>>(
                m1c, wtm2, bm2, m2c, CH, 768, 768, 768);
            seg768<<<GRIDN / 8, 256, 0, stream>>>(rs, e0, e0 + CH, m2c, sums);
        }

        mean_bf16<<<(GRIDN * 768 / 4 + 255) / 256, 256, 0, stream>>>(sums, rs, meanM2);
        // out = meanM2 @ wm3 + bm3   (f32, direct to d_out)
        mfma_gemm<false, true><<<dim3(3, 256), 256, 0, stream>>>(
            meanM2, wtm3, bm3, out, GRIDN, 384, 768, 384);
        fix_empty<<<(GRIDN + 255) / 256, 256, 0, stream>>>(rs, out);
    } else {
        // ================= FALLBACK: U/V path with w3-fold, CH=32768, 384-wide seg =================
        const int CH = 32768;
        const int NCH = NEDGE / CH;
        char* CA = alloc(2 * rnd((size_t)CH * 768 * 2));   // hosts meshf2+gridf pre-loop

        __hip_bfloat16* meshf2 = (__hip_bfloat16*)CA;
        __hip_bfloat16* gridf  = (__hip_bfloat16*)(CA + szMesh);
        __hip_bfloat16* m1c    = (__hip_bfloat16*)CA;
        __hip_bfloat16* m2c    = (__hip_bfloat16*)(CA + rnd((size_t)CH * 768 * 2));
        __hip_bfloat16* m3c    = m1c;

        hipMemsetAsync(out, 0, (size_t)GRIDN * HID * 4, stream);

        embed_kernel<<<(NMESH * 96 + 255) / 256, 256, 0, stream>>>(mesh_pos, meshf2, NMESH, 576, 384);
        embed_kernel<<<(GRIDN * 96 + 255) / 256, 256, 0, stream>>>(grid_pos, gridf, GRIDN, 192, 0);

        lin1_kernel<<<(NMESH * HID + 255) / 256, 256, 0, stream>>>(x, w1, b1, h1);

        mfma_gemm<true, false><<<dim3(3, 391), 256, 0, stream>>>(
            h1, wt2, b2, meshf2, NMESH, 384, 384, 576);
        mfma_gemm<false, false><<<dim3(6, 391), 256, 0, stream>>>(
            meshf2, wtm1f, bf, U, NMESH, 768, 576, 768);
        mfma_gemm<false, false><<<dim3(6, 256), 256, 0, stream>>>(
            gridf, wtm1v, zeros, V, GRIDN, 768, 192, 768);

        for (int c = 0; c < NCH; c++) {
            int e0 = c * CH;
            fuse_m1<<<(CH * 96 + 255) / 256, 256, 0, stream>>>(U, V, edges, e0, CH, m1c);
            mfma_gemm<true, false><<<dim3(6, CH / 128), 256, 0, stream>>>(
                m1c, wtm2, bm2, m2c, CH, 768, 768, 768);
            mfma_gemm<false, false><<<dim3(3, CH / 128), 256, 0, stream>>>(
                m2c, wtm3, bm3, m3c, CH, 384, 768, 384);
            seg_partial<<<GRIDN, 128, 0, stream>>>(edges, e0, e0 + CH, m3c, out);
        }

        seg_div<<<GRIDN, 128, 0, stream>>>(edges, out);
    }
}